// Round 1
// baseline (335.491 us; speedup 1.0000x reference)
//
#include <hip/hip_runtime.h>
#include <cstdint>
#include <cstddef>

// SpectralConv2d: out = real(ifft2(concat[einsum(fft2(x)[:, :64], w1),
//                                         zeros, einsum(fft2(x)[:, -64:], w2)]))
// B=16, S1=512, S2=64, M2=64, in=out=m1=m2=64.
// Only 128 of 512 s1-slices of fft2(x) are used; 384 of 512 output planes are 0.
//
// ws layout (needs 128 MB):
//   XFT_re [128j][16b][64kx][64ky] fp32   (32 MB)
//   XFT_im                                  (32 MB)
//   OFT_re [2set][16b][64o][64kx][64ky]     (32 MB)
//   OFT_im                                  (32 MB)

#define TWO_PI 6.283185307179586f

__device__ __forceinline__ constexpr int bitrev6(int x) {
    return ((x & 1) << 5) | ((x & 2) << 3) | ((x & 4) << 1) |
           ((x & 8) >> 1) | ((x & 16) >> 3) | ((x & 32) >> 5);
}

// In-register 64-point FFT, input already in bit-reversed order, output natural.
// Twiddle sign baked into tws (fwd: -sin, inv: +sin). twc/tws live in LDS;
// indices are compile-time after full unroll -> broadcast reads.
__device__ __forceinline__ void fft64_reg(float* re, float* im,
                                          const float* twc, const float* tws) {
#pragma unroll
    for (int s = 1; s <= 6; ++s) {
        const int m = 1 << s;
        const int h = m >> 1;
        const int step = 64 >> s;
#pragma unroll
        for (int k = 0; k < 64; k += m) {
#pragma unroll
            for (int j = 0; j < h; ++j) {
                const float wr = twc[j * step];
                const float wi = tws[j * step];
                const int p = k + j, q = p + h;
                const float tr = re[q] * wr - im[q] * wi;
                const float ti = re[q] * wi + im[q] * wr;
                re[q] = re[p] - tr; im[q] = im[p] - ti;
                re[p] = re[p] + tr; im[p] = im[p] + ti;
            }
        }
    }
}

// ---------------- forward: 2D FFT of 64x64 real tile ----------------
// grid.x = 2048 = b*128 + j ; j<64 -> s1=j (w1 slices), j>=64 -> s1=384+j (w2 slices)
__global__ __launch_bounds__(64) void fwd_fft_kernel(const float* __restrict__ x,
                                                     float* __restrict__ xre,
                                                     float* __restrict__ xim) {
    __shared__ float lre[64 * 65];
    __shared__ float lim[64 * 65];
    __shared__ float twc[64];
    __shared__ float tws[64];
    const int t = threadIdx.x;
    const int j = blockIdx.x & 127;
    const int b = blockIdx.x >> 7;
    const int s1 = (j < 64) ? j : (384 + j);

    const float ang = (TWO_PI / 64.0f) * (float)t;
    twc[t] = cosf(ang);
    tws[t] = -sinf(ang);   // forward

    const float* __restrict__ src = x + ((size_t)(b * 512 + s1)) * 4096;
#pragma unroll 8
    for (int k = 0; k < 64; ++k) lre[k * 65 + t] = src[k * 64 + t];  // coalesced
    __syncthreads();

    float are[64], aim[64];
    // row FFT: thread t owns row p = t (banks (t+q)%32 -> 2-way = free)
#pragma unroll
    for (int q = 0; q < 64; ++q) { are[q] = lre[t * 65 + bitrev6(q)]; aim[q] = 0.0f; }
    fft64_reg(are, aim, twc, tws);
#pragma unroll
    for (int q = 0; q < 64; ++q) { lre[t * 65 + q] = are[q]; lim[t * 65 + q] = aim[q]; }
    __syncthreads();

    // column FFT: thread t owns column ky = t
#pragma unroll
    for (int q = 0; q < 64; ++q) {
        const int r = bitrev6(q);
        are[q] = lre[r * 65 + t];
        aim[q] = lim[r * 65 + t];
    }
    fft64_reg(are, aim, twc, tws);

    float* __restrict__ dre = xre + (size_t)(j * 16 + b) * 4096;
    float* __restrict__ dim_ = xim + (size_t)(j * 16 + b) * 4096;
#pragma unroll 8
    for (int kp = 0; kp < 64; ++kp) {      // lanes = ky -> coalesced
        dre[kp * 64 + t] = are[kp];
        dim_[kp * 64 + t] = aim[kp];
    }
}

// ---------------- channel mix: per (kx,ky) complex*real GEMM ----------------
// grid (64 kx, 16 o-tiles of 4), block 256 = 4 waves; wave w -> b in [4w,4w+4); lane = ky.
__global__ __launch_bounds__(256) void mix_kernel(const float* __restrict__ xre,
                                                  const float* __restrict__ xim,
                                                  const float* __restrict__ w1,
                                                  const float* __restrict__ w2,
                                                  float* __restrict__ ore,
                                                  float* __restrict__ oim) {
    const int lane = threadIdx.x & 63;
    const int wv = threadIdx.x >> 6;
    const int kx = blockIdx.x;
    const int o0 = blockIdx.y * 4;

    float accRe[2][4][4] = {};
    float accIm[2][4][4] = {};

    for (int i = 0; i < 64; ++i) {
        float a1re[4], a1im[4], a2re[4], a2im[4];
#pragma unroll
        for (int bb = 0; bb < 4; ++bb) {
            const int b = wv * 4 + bb;
            const size_t p1 = ((size_t)(i * 16 + b) * 64 + kx) * 64 + lane;
            const size_t p2 = ((size_t)((64 + i) * 16 + b) * 64 + kx) * 64 + lane;
            a1re[bb] = xre[p1]; a1im[bb] = xim[p1];
            a2re[bb] = xre[p2]; a2im[bb] = xim[p2];
        }
#pragma unroll
        for (int oo = 0; oo < 4; ++oo) {
            const size_t wp = ((size_t)(i * 64 + (o0 + oo)) * 64 + kx) * 64 + lane;
            const float w1v = w1[wp];
            const float w2v = w2[wp];
#pragma unroll
            for (int bb = 0; bb < 4; ++bb) {
                accRe[0][bb][oo] += a1re[bb] * w1v;
                accIm[0][bb][oo] += a1im[bb] * w1v;
                accRe[1][bb][oo] += a2re[bb] * w2v;
                accIm[1][bb][oo] += a2im[bb] * w2v;
            }
        }
    }

#pragma unroll
    for (int set = 0; set < 2; ++set)
#pragma unroll
        for (int bb = 0; bb < 4; ++bb)
#pragma unroll
            for (int oo = 0; oo < 4; ++oo) {
                const size_t pl = (size_t)set * 1024 + (size_t)(wv * 4 + bb) * 64 + (o0 + oo);
                const size_t q = pl * 4096 + (size_t)kx * 64 + lane;
                ore[q] = accRe[set][bb][oo];
                oim[q] = accIm[set][bb][oo];
            }
}

// ---------------- inverse: 2D IFFT (complex->real) of 64x64 plane ----------------
// grid.x = 2048 planes = set*1024 + b*64 + o ; writes real part * (1/4096)
__global__ __launch_bounds__(64) void inv_fft_kernel(const float* __restrict__ ore,
                                                     const float* __restrict__ oim,
                                                     float* __restrict__ out) {
    __shared__ float lre[64 * 65];
    __shared__ float lim[64 * 65];
    __shared__ float twc[64];
    __shared__ float tws[64];
    const int t = threadIdx.x;
    const int pl = blockIdx.x;
    const int set = pl >> 10;
    const int b = (pl >> 6) & 15;
    const int o = pl & 63;

    const float ang = (TWO_PI / 64.0f) * (float)t;
    twc[t] = cosf(ang);
    tws[t] = sinf(ang);    // inverse

    const float* __restrict__ sre = ore + (size_t)pl * 4096;
    const float* __restrict__ sim = oim + (size_t)pl * 4096;
#pragma unroll 8
    for (int k = 0; k < 64; ++k) {
        lre[k * 65 + t] = sre[k * 64 + t];
        lim[k * 65 + t] = sim[k * 64 + t];
    }
    __syncthreads();

    float are[64], aim[64];
    // row IFFT over ky: thread t owns row kx = t
#pragma unroll
    for (int q = 0; q < 64; ++q) {
        const int r = bitrev6(q);
        are[q] = lre[t * 65 + r];
        aim[q] = lim[t * 65 + r];
    }
    fft64_reg(are, aim, twc, tws);
#pragma unroll
    for (int q = 0; q < 64; ++q) { lre[t * 65 + q] = are[q]; lim[t * 65 + q] = aim[q]; }
    __syncthreads();

    // column IFFT over kx: thread t owns column y = t
#pragma unroll
    for (int q = 0; q < 64; ++q) {
        const int r = bitrev6(q);
        are[q] = lre[r * 65 + t];
        aim[q] = lim[r * 65 + t];
    }
    fft64_reg(are, aim, twc, tws);

    const int s1 = set ? (448 + o) : o;
    float* __restrict__ dst = out + ((size_t)(b * 512 + s1)) * 4096;
#pragma unroll 8
    for (int p = 0; p < 64; ++p)
        dst[p * 64 + t] = are[p] * (1.0f / 4096.0f);
}

// ---------------- zero-fill out[:, 64:448, :, :] (exactly zero planes) ----------------
__global__ void zero_mid_kernel(float4* __restrict__ out) {
    const size_t per_b = (size_t)384 * 1024;  // float4 per batch mid-region
    const size_t i = (size_t)blockIdx.x * blockDim.x + threadIdx.x;
    if (i >= 16 * per_b) return;
    const size_t b = i / per_b;
    const size_t r = i - b * per_b;
    out[b * (512 * 1024) + 64 * 1024 + r] = make_float4(0.f, 0.f, 0.f, 0.f);
}

extern "C" void kernel_launch(void* const* d_in, const int* in_sizes, int n_in,
                              void* d_out, int out_size, void* d_ws, size_t ws_size,
                              hipStream_t stream) {
    const float* x  = (const float*)d_in[0];
    const float* w1 = (const float*)d_in[1];
    const float* w2 = (const float*)d_in[2];
    float* out = (float*)d_out;

    const size_t PLANE_FLOATS = (size_t)2048 * 4096;  // 8M floats = 32 MB
    float* xre = (float*)d_ws;
    float* xim = xre + PLANE_FLOATS;
    float* ore = xim + PLANE_FLOATS;
    float* oim = ore + PLANE_FLOATS;
    // requires ws_size >= 128 MB

    fwd_fft_kernel<<<2048, 64, 0, stream>>>(x, xre, xim);
    mix_kernel<<<dim3(64, 16), 256, 0, stream>>>(xre, xim, w1, w2, ore, oim);
    inv_fft_kernel<<<2048, 64, 0, stream>>>(ore, oim, out);

    const int zthreads = 256;
    const int zblocks = (int)(((size_t)16 * 384 * 1024 + zthreads - 1) / zthreads);
    zero_mid_kernel<<<zblocks, zthreads, 0, stream>>>((float4*)out);
}

// Round 2
// 234.938 us; speedup vs baseline: 1.4280x; 1.4280x over previous
//
#include <hip/hip_runtime.h>
#include <cstdint>
#include <cstddef>

// SpectralConv2d: out = real(ifft2(concat[einsum(fft2(x)[:, :64], w1),
//                                         zeros, einsum(fft2(x)[:, -64:], w2)]))
// B=16, S1=512, S2=64, M2=64, in=out=m1=m2=64.
// Only 128 of 512 s1-slices of fft2(x) are used; 384 of 512 output planes are 0.
//
// ws layout (needs 134 MB):
//   XFT_re [128j][16b][64kx][64ky] fp32   (33.5 MB)   j<64 -> s1=j ; j>=64 -> s1=384+j
//   XFT_im                                 (33.5 MB)
//   OFT_re [2set][16b][64o][64kx][64ky]    (33.5 MB)
//   OFT_im                                 (33.5 MB)

#define TWO_PI 6.283185307179586f

__device__ __forceinline__ constexpr int bitrev6(int x) {
    return ((x & 1) << 5) | ((x & 2) << 3) | ((x & 4) << 1) |
           ((x & 8) >> 1) | ((x & 16) >> 3) | ((x & 32) >> 5);
}

// In-register 64-point FFT, input already bit-reversed, output natural order.
// Fully unrolled -> all register indices static (NO scratch). Twiddle sign
// baked into tws (fwd: -sin, inv: +sin); broadcast LDS reads (static idx).
__device__ __forceinline__ void fft64_reg(float* re, float* im,
                                          const float* twc, const float* tws) {
#pragma unroll
    for (int s = 1; s <= 6; ++s) {
        const int m = 1 << s;
        const int h = m >> 1;
        const int step = 64 >> s;
#pragma unroll
        for (int k = 0; k < 64; k += m) {
#pragma unroll
            for (int j = 0; j < h; ++j) {
                const float wr = twc[j * step];
                const float wi = tws[j * step];
                const int p = k + j, q = p + h;
                const float tr = re[q] * wr - im[q] * wi;
                const float ti = re[q] * wi + im[q] * wr;
                re[q] = re[p] - tr; im[q] = im[p] - ti;
                re[p] = re[p] + tr; im[p] = im[p] + ti;
            }
        }
    }
}

// ---------------- forward: 2D FFT of 64x64 real tile ----------------
// grid.x = 2048 = b*128 + j ; j<64 -> s1=j (w1 slices), j>=64 -> s1=384+j (w2)
__global__ __launch_bounds__(64, 1) void fwd_fft_kernel(const float* __restrict__ x,
                                                        float* __restrict__ xre,
                                                        float* __restrict__ xim) {
    __shared__ float lre[64 * 65];
    __shared__ float lim[64 * 65];
    __shared__ float twc[64];
    __shared__ float tws[64];
    const int t = threadIdx.x;
    const int j = blockIdx.x & 127;
    const int b = blockIdx.x >> 7;
    const int s1 = (j < 64) ? j : (384 + j);

    const float ang = (TWO_PI / 64.0f) * (float)t;
    twc[t] = cosf(ang);
    tws[t] = -sinf(ang);   // forward

    const float* __restrict__ src = x + ((size_t)(b * 512 + s1)) * 4096;
#pragma unroll
    for (int k = 0; k < 64; ++k) lre[k * 65 + t] = src[k * 64 + t];  // coalesced
    __syncthreads();

    float are[64], aim[64];
    // row FFT: thread t owns row t  (banks (t+q)%32 -> 2-way aliasing = free)
#pragma unroll
    for (int q = 0; q < 64; ++q) { are[q] = lre[t * 65 + bitrev6(q)]; aim[q] = 0.0f; }
    fft64_reg(are, aim, twc, tws);
#pragma unroll
    for (int q = 0; q < 64; ++q) { lre[t * 65 + q] = are[q]; lim[t * 65 + q] = aim[q]; }
    __syncthreads();

    // column FFT: thread t owns column ky = t
#pragma unroll
    for (int q = 0; q < 64; ++q) {
        const int r = bitrev6(q);
        are[q] = lre[r * 65 + t];
        aim[q] = lim[r * 65 + t];
    }
    fft64_reg(are, aim, twc, tws);

    float* __restrict__ dre = xre + (size_t)(j * 16 + b) * 4096;
    float* __restrict__ dim_ = xim + (size_t)(j * 16 + b) * 4096;
#pragma unroll
    for (int kp = 0; kp < 64; ++kp) {      // lanes = ky -> coalesced; FULL unroll
        dre[kp * 64 + t] = are[kp];
        dim_[kp * 64 + t] = aim[kp];
    }
}

// ---------------- channel mix: per (kx,ky) complex*real GEMM ----------------
// grid (kx=64, o-tile=4, set=2), block 256.
// Thread t: kyg=t&15 (ky quad), u=t>>4: bq=u>>2 (4 b each), oq=u&3 (4 o each).
// Block covers ALL 16 b for its (set, kx, 16-o tile) -> each weight element
// fetched exactly once from HBM across the whole grid.
__device__ __forceinline__ void fma4(float4& a, const float4& x, const float4& w) {
    a.x += x.x * w.x; a.y += x.y * w.y; a.z += x.z * w.z; a.w += x.w * w.w;
}

__global__ __launch_bounds__(256, 2) void mix_kernel(const float* __restrict__ xre,
                                                     const float* __restrict__ xim,
                                                     const float* __restrict__ w1,
                                                     const float* __restrict__ w2,
                                                     float* __restrict__ ore,
                                                     float* __restrict__ oim) {
    const int t = threadIdx.x;
    const int kyg = t & 15;
    const int u = t >> 4;
    const int bq = u >> 2;
    const int oq = u & 3;
    const int kx = blockIdx.x;
    const int o0 = blockIdx.y * 16;
    const int set = blockIdx.z;
    const float* __restrict__ w = set ? w2 : w1;
    const int ky0 = kyg * 4;
    const int fx = kx * 64 + ky0;

    float4 accRe[4][4];   // [bb][oo]
    float4 accIm[4][4];
#pragma unroll
    for (int bb = 0; bb < 4; ++bb)
#pragma unroll
        for (int oo = 0; oo < 4; ++oo) {
            accRe[bb][oo] = make_float4(0.f, 0.f, 0.f, 0.f);
            accIm[bb][oo] = make_float4(0.f, 0.f, 0.f, 0.f);
        }

#pragma unroll 2
    for (int i = 0; i < 64; ++i) {
        float4 xr[4], xi[4];
#pragma unroll
        for (int bb = 0; bb < 4; ++bb) {
            const size_t p = ((size_t)((set * 64 + i) * 16 + (bq * 4 + bb)) << 12) + fx;
            xr[bb] = *(const float4*)(xre + p);
            xi[bb] = *(const float4*)(xim + p);
        }
        float4 wv[4];
#pragma unroll
        for (int oo = 0; oo < 4; ++oo) {
            const size_t q = ((size_t)(i * 64 + o0 + oq * 4 + oo) << 12) + fx;
            wv[oo] = *(const float4*)(w + q);
        }
#pragma unroll
        for (int bb = 0; bb < 4; ++bb)
#pragma unroll
            for (int oo = 0; oo < 4; ++oo) {
                fma4(accRe[bb][oo], xr[bb], wv[oo]);
                fma4(accIm[bb][oo], xi[bb], wv[oo]);
            }
    }

#pragma unroll
    for (int bb = 0; bb < 4; ++bb)
#pragma unroll
        for (int oo = 0; oo < 4; ++oo) {
            const size_t pl = (size_t)set * 1024 + (size_t)(bq * 4 + bb) * 64 + (o0 + oq * 4 + oo);
            const size_t q = (pl << 12) + fx;
            *(float4*)(ore + q) = accRe[bb][oo];
            *(float4*)(oim + q) = accIm[bb][oo];
        }
}

// ---------------- inverse: 2D IFFT (complex->real) of 64x64 plane ----------------
// grid.x = 2048 planes = set*1024 + b*64 + o ; writes real part * (1/4096)
__global__ __launch_bounds__(64, 1) void inv_fft_kernel(const float* __restrict__ ore,
                                                        const float* __restrict__ oim,
                                                        float* __restrict__ out) {
    __shared__ float lre[64 * 65];
    __shared__ float lim[64 * 65];
    __shared__ float twc[64];
    __shared__ float tws[64];
    const int t = threadIdx.x;
    const int pl = blockIdx.x;
    const int set = pl >> 10;
    const int b = (pl >> 6) & 15;
    const int o = pl & 63;

    const float ang = (TWO_PI / 64.0f) * (float)t;
    twc[t] = cosf(ang);
    tws[t] = sinf(ang);    // inverse

    const float* __restrict__ sre = ore + (size_t)pl * 4096;
    const float* __restrict__ sim = oim + (size_t)pl * 4096;
#pragma unroll
    for (int k = 0; k < 64; ++k) {
        lre[k * 65 + t] = sre[k * 64 + t];
        lim[k * 65 + t] = sim[k * 64 + t];
    }
    __syncthreads();

    float are[64], aim[64];
    // row IFFT over ky: thread t owns row kx = t
#pragma unroll
    for (int q = 0; q < 64; ++q) {
        const int r = bitrev6(q);
        are[q] = lre[t * 65 + r];
        aim[q] = lim[t * 65 + r];
    }
    fft64_reg(are, aim, twc, tws);
#pragma unroll
    for (int q = 0; q < 64; ++q) { lre[t * 65 + q] = are[q]; lim[t * 65 + q] = aim[q]; }
    __syncthreads();

    // column IFFT over kx: thread t owns column y = t
#pragma unroll
    for (int q = 0; q < 64; ++q) {
        const int r = bitrev6(q);
        are[q] = lre[r * 65 + t];
        aim[q] = lim[r * 65 + t];
    }
    fft64_reg(are, aim, twc, tws);

    const int s1 = set ? (448 + o) : o;
    float* __restrict__ dst = out + ((size_t)(b * 512 + s1)) * 4096;
#pragma unroll
    for (int p = 0; p < 64; ++p)        // FULL unroll -> static reg indices
        dst[p * 64 + t] = are[p] * (1.0f / 4096.0f);
}

// ---------------- zero-fill out[:, 64:448, :, :] (exactly zero planes) ----------------
__global__ void zero_mid_kernel(float4* __restrict__ out) {
    const size_t per_b = (size_t)384 * 1024;  // float4 per batch mid-region
    const size_t i = (size_t)blockIdx.x * blockDim.x + threadIdx.x;
    if (i >= 16 * per_b) return;
    const size_t b = i / per_b;
    const size_t r = i - b * per_b;
    out[b * (512 * 1024) + 64 * 1024 + r] = make_float4(0.f, 0.f, 0.f, 0.f);
}

extern "C" void kernel_launch(void* const* d_in, const int* in_sizes, int n_in,
                              void* d_out, int out_size, void* d_ws, size_t ws_size,
                              hipStream_t stream) {
    const float* x  = (const float*)d_in[0];
    const float* w1 = (const float*)d_in[1];
    const float* w2 = (const float*)d_in[2];
    float* out = (float*)d_out;

    const size_t PLANE_FLOATS = (size_t)2048 * 4096;  // 8.39M floats = 33.5 MB
    float* xre = (float*)d_ws;
    float* xim = xre + PLANE_FLOATS;
    float* ore = xim + PLANE_FLOATS;
    float* oim = ore + PLANE_FLOATS;
    // requires ws_size >= 134 MB

    fwd_fft_kernel<<<2048, 64, 0, stream>>>(x, xre, xim);
    mix_kernel<<<dim3(64, 4, 2), 256, 0, stream>>>(xre, xim, w1, w2, ore, oim);
    inv_fft_kernel<<<2048, 64, 0, stream>>>(ore, oim, out);

    const int zthreads = 256;
    const int zblocks = (int)(((size_t)16 * 384 * 1024 + zthreads - 1) / zthreads);
    zero_mid_kernel<<<zblocks, zthreads, 0, stream>>>((float4*)out);
}

// Round 3
// 222.305 us; speedup vs baseline: 1.5091x; 1.0568x over previous
//
#include <hip/hip_runtime.h>
#include <cstdint>
#include <cstddef>

// SpectralConv2d: out = real(ifft2(concat[einsum(fft2(x)[:, :64], w1),
//                                         zeros, einsum(fft2(x)[:, -64:], w2)]))
// B=16, S1=512, S2=64, M2=64, in=out=m1=m2=64.
// Only 128 of 512 s1-slices of fft2(x) are used; 384 of 512 output planes are 0.
//
// ws layout (needs 134 MB):
//   XFT_re [128j][16b][64kx][64ky] fp32   (33.5 MB)   j<64 -> s1=j ; j>=64 -> s1=384+j
//   XFT_im                                 (33.5 MB)
//   OFT_re [2set][16b][64o][64kx][64ky]    (33.5 MB)
//   OFT_im                                 (33.5 MB)

#define TWO_PI 6.283185307179586f

__device__ __forceinline__ constexpr int bitrev6(int x) {
    return ((x & 1) << 5) | ((x & 2) << 3) | ((x & 4) << 1) |
           ((x & 8) >> 1) | ((x & 16) >> 3) | ((x & 32) >> 5);
}

// In-register 64-point FFT, input already bit-reversed, output natural order.
// Fully unrolled -> all register indices static (NO scratch).
__device__ __forceinline__ void fft64_reg(float* re, float* im,
                                          const float* twc, const float* tws) {
#pragma unroll
    for (int s = 1; s <= 6; ++s) {
        const int m = 1 << s;
        const int h = m >> 1;
        const int step = 64 >> s;
#pragma unroll
        for (int k = 0; k < 64; k += m) {
#pragma unroll
            for (int j = 0; j < h; ++j) {
                const float wr = twc[j * step];
                const float wi = tws[j * step];
                const int p = k + j, q = p + h;
                const float tr = re[q] * wr - im[q] * wi;
                const float ti = re[q] * wi + im[q] * wr;
                re[q] = re[p] - tr; im[q] = im[p] - ti;
                re[p] = re[p] + tr; im[p] = im[p] + ti;
            }
        }
    }
}

// ---------------- forward: 2D FFT of 64x64 real tile ----------------
// grid.x = 2048 = b*128 + j ; j<64 -> s1=j (w1 slices), j>=64 -> s1=384+j (w2)
__global__ __launch_bounds__(64, 1) void fwd_fft_kernel(const float* __restrict__ x,
                                                        float* __restrict__ xre,
                                                        float* __restrict__ xim) {
    __shared__ float lre[64 * 65];
    __shared__ float lim[64 * 65];
    __shared__ float twc[64];
    __shared__ float tws[64];
    const int t = threadIdx.x;
    const int j = blockIdx.x & 127;
    const int b = blockIdx.x >> 7;
    const int s1 = (j < 64) ? j : (384 + j);

    const float ang = (TWO_PI / 64.0f) * (float)t;
    twc[t] = cosf(ang);
    tws[t] = -sinf(ang);   // forward

    const float* __restrict__ src = x + ((size_t)(b * 512 + s1)) * 4096;
#pragma unroll
    for (int k = 0; k < 64; ++k) lre[k * 65 + t] = src[k * 64 + t];  // coalesced
    __syncthreads();

    float are[64], aim[64];
    // row FFT: thread t owns row t  (banks (t+q)%32 -> 2-way aliasing = free)
#pragma unroll
    for (int q = 0; q < 64; ++q) { are[q] = lre[t * 65 + bitrev6(q)]; aim[q] = 0.0f; }
    fft64_reg(are, aim, twc, tws);
#pragma unroll
    for (int q = 0; q < 64; ++q) { lre[t * 65 + q] = are[q]; lim[t * 65 + q] = aim[q]; }
    __syncthreads();

    // column FFT: thread t owns column ky = t
#pragma unroll
    for (int q = 0; q < 64; ++q) {
        const int r = bitrev6(q);
        are[q] = lre[r * 65 + t];
        aim[q] = lim[r * 65 + t];
    }
    fft64_reg(are, aim, twc, tws);

    float* __restrict__ dre = xre + (size_t)(j * 16 + b) * 4096;
    float* __restrict__ dim_ = xim + (size_t)(j * 16 + b) * 4096;
#pragma unroll
    for (int kp = 0; kp < 64; ++kp) {      // lanes = ky -> coalesced; FULL unroll
        dre[kp * 64 + t] = are[kp];
        dim_[kp * 64 + t] = aim[kp];
    }
}

// ---------------- channel mix: per (kx,ky) complex*real GEMM ----------------
// grid (kx=64, o-tile=8, set=2) = 1024 blocks -> exactly 4 blocks/CU resident.
// Thread t: kyg=t&15 (ky quad), u=t>>4: bq=u>>2 (4 b each), oq=u&3 (2 o each).
// acc = 4b x 2o x float4(ky) x {re,im} = 64 VGPRs  (fits 128-reg budget @4w/SIMD).
// Weights: each element fetched exactly once from HBM across the whole grid.
__device__ __forceinline__ void fma4(float4& a, const float4& x, const float4& w) {
    a.x += x.x * w.x; a.y += x.y * w.y; a.z += x.z * w.z; a.w += x.w * w.w;
}

__global__ __launch_bounds__(256, 4) void mix_kernel(const float* __restrict__ xre,
                                                     const float* __restrict__ xim,
                                                     const float* __restrict__ w1,
                                                     const float* __restrict__ w2,
                                                     float* __restrict__ ore,
                                                     float* __restrict__ oim) {
    const int t = threadIdx.x;
    const int kyg = t & 15;
    const int u = t >> 4;
    const int bq = u >> 2;      // b = bq*4 + bb
    const int oq = u & 3;       // o = o0 + oq*2 + oo
    const int kx = blockIdx.x;
    const int o0 = blockIdx.y * 8;
    const int set = blockIdx.z;
    const float* __restrict__ w = set ? w2 : w1;
    const int fx = kx * 64 + kyg * 4;

    float4 accRe[4][2] = {};
    float4 accIm[4][2] = {};

    const float* __restrict__ xrb = xre + ((size_t)(set * 64 * 16 + bq * 4)) * 4096 + fx;
    const float* __restrict__ xib = xim + ((size_t)(set * 64 * 16 + bq * 4)) * 4096 + fx;
    const float* __restrict__ wb  = w   + ((size_t)(o0 + oq * 2)) * 4096 + fx;

    for (int i = 0; i < 64; ++i) {
        const float* __restrict__ xr_i = xrb + (size_t)i * (16 * 4096);
        const float* __restrict__ xi_i = xib + (size_t)i * (16 * 4096);
        const float* __restrict__ w_i  = wb  + (size_t)i * (64 * 4096);
        const float4 wv0 = *(const float4*)(w_i);
        const float4 wv1 = *(const float4*)(w_i + 4096);
#pragma unroll
        for (int bb = 0; bb < 4; ++bb) {
            const float4 xr = *(const float4*)(xr_i + bb * 4096);
            const float4 xi = *(const float4*)(xi_i + bb * 4096);
            fma4(accRe[bb][0], xr, wv0);
            fma4(accRe[bb][1], xr, wv1);
            fma4(accIm[bb][0], xi, wv0);
            fma4(accIm[bb][1], xi, wv1);
        }
    }

#pragma unroll
    for (int bb = 0; bb < 4; ++bb)
#pragma unroll
        for (int oo = 0; oo < 2; ++oo) {
            const size_t pl = (size_t)set * 1024 + (size_t)(bq * 4 + bb) * 64 + (o0 + oq * 2 + oo);
            const size_t q = (pl << 12) + fx;
            *(float4*)(ore + q) = accRe[bb][oo];
            *(float4*)(oim + q) = accIm[bb][oo];
        }
}

// ---------------- inverse: 2D IFFT (complex->real) of 64x64 plane ----------------
// grid.x = 2048 planes = set*1024 + b*64 + o ; writes real part * (1/4096)
__global__ __launch_bounds__(64, 1) void inv_fft_kernel(const float* __restrict__ ore,
                                                        const float* __restrict__ oim,
                                                        float* __restrict__ out) {
    __shared__ float lre[64 * 65];
    __shared__ float lim[64 * 65];
    __shared__ float twc[64];
    __shared__ float tws[64];
    const int t = threadIdx.x;
    const int pl = blockIdx.x;
    const int set = pl >> 10;
    const int b = (pl >> 6) & 15;
    const int o = pl & 63;

    const float ang = (TWO_PI / 64.0f) * (float)t;
    twc[t] = cosf(ang);
    tws[t] = sinf(ang);    // inverse

    const float* __restrict__ sre = ore + (size_t)pl * 4096;
    const float* __restrict__ sim = oim + (size_t)pl * 4096;
#pragma unroll
    for (int k = 0; k < 64; ++k) {
        lre[k * 65 + t] = sre[k * 64 + t];
        lim[k * 65 + t] = sim[k * 64 + t];
    }
    __syncthreads();

    float are[64], aim[64];
    // row IFFT over ky: thread t owns row kx = t
#pragma unroll
    for (int q = 0; q < 64; ++q) {
        const int r = bitrev6(q);
        are[q] = lre[t * 65 + r];
        aim[q] = lim[t * 65 + r];
    }
    fft64_reg(are, aim, twc, tws);
#pragma unroll
    for (int q = 0; q < 64; ++q) { lre[t * 65 + q] = are[q]; lim[t * 65 + q] = aim[q]; }
    __syncthreads();

    // column IFFT over kx: thread t owns column y = t
#pragma unroll
    for (int q = 0; q < 64; ++q) {
        const int r = bitrev6(q);
        are[q] = lre[r * 65 + t];
        aim[q] = lim[r * 65 + t];
    }
    fft64_reg(are, aim, twc, tws);

    const int s1 = set ? (448 + o) : o;
    float* __restrict__ dst = out + ((size_t)(b * 512 + s1)) * 4096;
#pragma unroll
    for (int p = 0; p < 64; ++p)        // FULL unroll -> static reg indices
        dst[p * 64 + t] = are[p] * (1.0f / 4096.0f);
}

// ---------------- zero-fill out[:, 64:448, :, :] (exactly zero planes) ----------------
__global__ void zero_mid_kernel(float4* __restrict__ out) {
    const size_t per_b = (size_t)384 * 1024;  // float4 per batch mid-region
    const size_t i = (size_t)blockIdx.x * blockDim.x + threadIdx.x;
    if (i >= 16 * per_b) return;
    const size_t b = i / per_b;
    const size_t r = i - b * per_b;
    out[b * (512 * 1024) + 64 * 1024 + r] = make_float4(0.f, 0.f, 0.f, 0.f);
}

extern "C" void kernel_launch(void* const* d_in, const int* in_sizes, int n_in,
                              void* d_out, int out_size, void* d_ws, size_t ws_size,
                              hipStream_t stream) {
    const float* x  = (const float*)d_in[0];
    const float* w1 = (const float*)d_in[1];
    const float* w2 = (const float*)d_in[2];
    float* out = (float*)d_out;

    const size_t PLANE_FLOATS = (size_t)2048 * 4096;  // 8.39M floats = 33.5 MB
    float* xre = (float*)d_ws;
    float* xim = xre + PLANE_FLOATS;
    float* ore = xim + PLANE_FLOATS;
    float* oim = ore + PLANE_FLOATS;
    // requires ws_size >= 134 MB

    fwd_fft_kernel<<<2048, 64, 0, stream>>>(x, xre, xim);
    mix_kernel<<<dim3(64, 8, 2), 256, 0, stream>>>(xre, xim, w1, w2, ore, oim);
    inv_fft_kernel<<<2048, 64, 0, stream>>>(ore, oim, out);

    const int zthreads = 256;
    const int zblocks = (int)(((size_t)16 * 384 * 1024 + zthreads - 1) / zthreads);
    zero_mid_kernel<<<zblocks, zthreads, 0, stream>>>((float4*)out);
}